// Round 6
// baseline (17525.227 us; speedup 1.0000x reference)
//
#include <hip/hip_runtime.h>

// Persistent wavefront-pipelined LSTMP (3 layers), split-bf16 MFMA emulating fp32.
// Round 6: 32 fat blocks/layer (grid 96), each does gates for 32 units (A) AND
// projection for 16 cols (C). No global barrier, no shared counters: per-block
// monotone flag ARRAYS (distinct cache lines), polled by 32 lanes of wave 0.
// h is 4-deep (mod-4) buffered; WAR guarded by mflag[l+1][*] >= t-3.

typedef short s16x4 __attribute__((ext_vector_type(4)));
typedef short s16x8 __attribute__((ext_vector_type(8)));
typedef float f32x4 __attribute__((ext_vector_type(4)));

#define MFMA16(a,b,c) __builtin_amdgcn_mfma_f32_16x16x32_bf16((a),(b),(c),0,0,0)

__device__ __forceinline__ unsigned short f2bf(float f) {
  unsigned int u = __builtin_bit_cast(unsigned int, f);
  u += 0x7FFFu + ((u >> 16) & 1u);          // RNE
  return (unsigned short)(u >> 16);
}
__device__ __forceinline__ float bf2f(unsigned short h) {
  unsigned int u = ((unsigned int)h) << 16;
  return __builtin_bit_cast(float, u);
}
__device__ __forceinline__ float fsig(float x)  { return __fdividef(1.0f, 1.0f + __expf(-x)); }
__device__ __forceinline__ float ftanh(float x) { return 1.0f - __fdividef(2.0f, 1.0f + __expf(2.0f * x)); }

// Coherent (LIC) 16B read as two relaxed agent-scope 8B atomic loads.
__device__ __forceinline__ s16x8 cload(const unsigned short* p) {
  unsigned long long a = __hip_atomic_load((unsigned long long*)p,       __ATOMIC_RELAXED, __HIP_MEMORY_SCOPE_AGENT);
  unsigned long long b = __hip_atomic_load((unsigned long long*)(p + 4), __ATOMIC_RELAXED, __HIP_MEMORY_SCOPE_AGENT);
  s16x4 x = __builtin_bit_cast(s16x4, a);
  s16x4 y = __builtin_bit_cast(s16x4, b);
  s16x8 r = {x[0], x[1], x[2], x[3], y[0], y[1], y[2], y[3]};
  return r;
}
__device__ __forceinline__ void cstore2(unsigned short* p, unsigned short a, unsigned short b) {
  unsigned int v = (unsigned int)a | ((unsigned int)b << 16);
  __hip_atomic_store((unsigned int*)p, v, __ATOMIC_RELAXED, __HIP_MEMORY_SCOPE_AGENT);
}
__device__ __forceinline__ void flag_wait_ge(const unsigned int* f, unsigned int target) {
  while (__hip_atomic_load(f, __ATOMIC_RELAXED, __HIP_MEMORY_SCOPE_AGENT) < target) {
    __builtin_amdgcn_s_sleep(1);
  }
}

// Relaxed sense-counting grid barrier (init only; 96 blocks).
__device__ __forceinline__ void gbar(unsigned int* bar, unsigned int* rel, unsigned int seq) {
  __syncthreads();
  asm volatile("" ::: "memory");
  if (blockIdx.x == 0) {
    const int tid = threadIdx.x;
    if (tid > 0 && tid < 96) {
      while (__hip_atomic_load(&bar[tid * 16], __ATOMIC_RELAXED, __HIP_MEMORY_SCOPE_AGENT) != seq) {
        __builtin_amdgcn_s_sleep(1);
      }
    }
    __syncthreads();
    if (tid == 0) {
      __hip_atomic_store(rel, seq, __ATOMIC_RELAXED, __HIP_MEMORY_SCOPE_AGENT);
    }
  } else {
    if (threadIdx.x == 0) {
      __hip_atomic_store(&bar[blockIdx.x * 16], seq, __ATOMIC_RELAXED, __HIP_MEMORY_SCOPE_AGENT);
      while (__hip_atomic_load(rel, __ATOMIC_RELAXED, __HIP_MEMORY_SCOPE_AGENT) != seq) {
        __builtin_amdgcn_s_sleep(1);
      }
    }
    __syncthreads();
  }
  asm volatile("" ::: "memory");
}

__global__ __launch_bounds__(512) void lstmp_persist(
    const float* __restrict__ x,
    const float* __restrict__ W0, const float* __restrict__ b0, const float* __restrict__ P0,
    const float* __restrict__ pi0, const float* __restrict__ pf0, const float* __restrict__ po0,
    const float* __restrict__ W1, const float* __restrict__ b1, const float* __restrict__ P1,
    const float* __restrict__ pi1, const float* __restrict__ pf1, const float* __restrict__ po1,
    const float* __restrict__ W2, const float* __restrict__ b2, const float* __restrict__ P2,
    const float* __restrict__ pi2, const float* __restrict__ pf2, const float* __restrict__ po2,
    float* __restrict__ out, unsigned char* __restrict__ ws)
{
  const int tid  = threadIdx.x;
  const int bid  = blockIdx.x;
  const int lane = tid & 63;
  const int wv   = tid >> 6;             // 0..7
  const int quad8 = (lane >> 4) * 8;
  const int nrow  = lane & 15;

  // ---- workspace carve ----
  unsigned int* bar    = (unsigned int*)ws;   // 96 slots * 16 uints (init barrier)
  unsigned int* rel    = bar + 3072;
  unsigned int* mflag0 = bar + 3104;          // 3*32 flags, 16-uint spaced (1536)
  unsigned int* hflag0 = mflag0 + 1536;       // 3*32 flags, 16-uint spaced (1536)
  unsigned short* xhi = (unsigned short*)(ws + 32768);
  unsigned short* xlo  = xhi  + 4096000;   // 500*32*256
  unsigned short* hhi  = xlo  + 4096000;   // 4 bufs * 3*32*512 = 196608
  unsigned short* hlo  = hhi  + 196608;
  unsigned short* mhi  = hlo  + 196608;    // 3*32*1024
  unsigned short* mlo  = mhi  + 98304;
  unsigned short* wBh0 = mlo  + 98304;     // 256*24*512
  unsigned short* wBl0 = wBh0 + 3145728;
  unsigned short* wBh1 = wBl0 + 3145728;   // 256*32*512
  unsigned short* wBl1 = wBh1 + 4194304;
  unsigned short* wBh2 = wBl1 + 4194304;
  unsigned short* wBl2 = wBh2 + 4194304;
  unsigned short* wPh  = wBl2 + 4194304;   // 3 * 32*32*512
  unsigned short* wPl  = wPh  + 1572864;

  const float* Wsrc[3] = {W0, W1, W2};
  const float* Psrc[3] = {P0, P1, P2};
  const float* Bsrc[3] = {b0, b1, b2};
  const float* PIs[3]  = {pi0, pi1, pi2};
  const float* PFs[3]  = {pf0, pf1, pf2};
  const float* POs[3]  = {po0, po1, po2};
  unsigned short* wBhv[3] = {wBh0, wBh1, wBh2};
  unsigned short* wBlv[3] = {wBl0, wBl1, wBl2};
  const int NKBv[3]    = {24, 32, 32};
  const int NKBINv[3]  = {8, 16, 16};
  const int KINPADv[3] = {256, 512, 512};
  const int KWv[3]     = {752, 1024, 1024};
  const int NINv[3]    = {240, 512, 512};

  __shared__ float exch[4][4][2][512];  // 64 KB: [kgroup][gate][unit-subtile][b*16+u16]
  __shared__ float c_lds[1024];         // persistent cell state: [b*32 + u]

  const unsigned int NT = 96u * 512u;
  const unsigned int gtid = (unsigned int)bid * 512u + (unsigned int)tid;

  // ================= INIT (ws re-poisoned every launch) =================
  for (unsigned int i = gtid; i < 3072u; i += NT) mflag0[i] = 0;  // mflag+hflag
  for (unsigned int i = gtid; i < 4096000u; i += NT) {
    unsigned int k = i & 255u, tb = i >> 8;
    float v = (k < 240u) ? x[tb * 240u + k] : 0.0f;
    unsigned short h = f2bf(v);
    xhi[i] = h; xlo[i] = f2bf(v - bf2f(h));
  }
  for (unsigned int i = gtid; i < 196608u; i += NT) { hhi[i] = 0; hlo[i] = 0; }
  for (int l = 0; l < 3; ++l) {
    const unsigned int nkb = (unsigned int)NKBv[l];
    const unsigned int tot = 256u * nkb * 512u;
    const float* Wl = Wsrc[l];
    unsigned short* dh = wBhv[l];
    unsigned short* dl = wBlv[l];
    const int kinpad = KINPADv[l], kw = KWv[l], nin = NINv[l];
    for (unsigned int i = gtid; i < tot; i += NT) {
      unsigned int j  = i & 7u;
      unsigned int ln = (i >> 3) & 63u;
      unsigned int kb = (i >> 9) % nkb;
      unsigned int gt = i / (nkb * 512u);
      unsigned int g  = gt * 16u + (ln & 15u);
      int k = (int)(kb * 32u + ((ln >> 4) * 8u) + j);
      float v;
      if (k < kinpad) v = (l == 0 && k >= 240) ? 0.0f : Wl[(size_t)g * kw + k];
      else            v = Wl[(size_t)g * kw + (k - kinpad + nin)];
      unsigned short h = f2bf(v);
      dh[i] = h; dl[i] = f2bf(v - bf2f(h));
    }
  }
  for (int l = 0; l < 3; ++l) {
    const float* Pl = Psrc[l];
    unsigned short* dh = wPh + (size_t)l * 524288u;
    unsigned short* dl = wPl + (size_t)l * 524288u;
    for (unsigned int i = gtid; i < 524288u; i += NT) {
      unsigned int j  = i & 7u;
      unsigned int ln = (i >> 3) & 63u;
      unsigned int kb = (i >> 9) & 31u;
      unsigned int pt = i >> 14;
      unsigned int prow = pt * 16u + (ln & 15u);
      int k = (int)(kb * 32u + ((ln >> 4) * 8u) + j);
      float v = Pl[(size_t)prow * 1024u + k];
      unsigned short h = f2bf(v);
      dh[i] = h; dl[i] = f2bf(v - bf2f(h));
    }
  }
  c_lds[tid] = 0.0f; c_lds[tid + 512] = 0.0f;

  __builtin_amdgcn_fence(__ATOMIC_RELEASE, "agent");
  gbar(bar, rel, 1u);
  __builtin_amdgcn_fence(__ATOMIC_ACQUIRE, "agent");

  // ---- fixed per-block roles: grid = 96 = 3 layers x 32 blocks ----
  const int lA = bid >> 5;           // layer 0..2
  const int lb = bid & 31;           // block-in-layer: owns units lb*32..+31 (A), cols lb*16..+15 (C)

  const int nkbA    = NKBv[lA];
  const int nkbinA  = NKBINv[lA];
  const int kinpadA = KINPADv[lA];
  const int kbwA    = nkbA >> 2;     // k-blocks per A-wave kgroup: 6 or 8

  // A-wave roles: ut = unit-subtile (16 units), kg = k-group
  const int utW = wv & 1;
  const int kgW = wv >> 1;
  // C-wave roles: mt = batch-half, kg2 = k-group (8 kb each)
  const int mtW  = wv & 1;
  const int kg2W = wv >> 1;

  unsigned int* mflagL  = mflag0 + lA * 512;          // [32] x 16-spaced
  unsigned int* mflagL1 = mflag0 + (lA + 1) * 512;    // only if lA<2
  unsigned int* hflagL  = hflag0 + lA * 512;
  unsigned int* hflagLm = hflag0 + (lA - 1) * 512;    // only if lA>0

  for (int t = 0; t < 500; ++t) {
    // ============ A-wait: h_{l-1}(t) ready AND own h(t-1) ready ============
    if (wv == 0) {
      if (lane < 32) {
        if (lA > 0) flag_wait_ge(hflagLm + lane * 16, (unsigned)(t + 1));
      } else {
        if (t > 0)  flag_wait_ge(hflagL + (lane - 32) * 16, (unsigned)t);
      }
    }
    __syncthreads();

    // ============ PHASE A: gates GEMM ============
    f32x4 acc[4][2];
    #pragma unroll
    for (int g = 0; g < 4; ++g) { acc[g][0] = {0.f,0.f,0.f,0.f}; acc[g][1] = {0.f,0.f,0.f,0.f}; }

    const unsigned short* wbh = wBhv[lA];
    const unsigned short* wbl = wBlv[lA];
    const unsigned short* ibh = hhi + (size_t)(t & 3) * 49152;        // h_{l-1}(t)
    const unsigned short* ibl = hlo + (size_t)(t & 3) * 49152;
    const unsigned short* rbh = hhi + (size_t)((t + 3) & 3) * 49152;  // h_l(t-1)
    const unsigned short* rbl = hlo + (size_t)((t + 3) & 3) * 49152;
    const int kb0 = kgW * kbwA, kb1 = kb0 + kbwA;
    const int gtb = lb * 2 + utW;  // 16-unit tile index within 64

    #pragma unroll 2
    for (int kb = kb0; kb < kb1; ++kb) {
      s16x8 fa0h, fa0l, fa1h, fa1l;
      if (kb < nkbinA) {
        if (lA == 0) {
          const unsigned short* ph = xhi + (size_t)(t * 32 + nrow) * 256 + kb * 32 + quad8;
          const unsigned short* pl = xlo + (size_t)(t * 32 + nrow) * 256 + kb * 32 + quad8;
          fa0h = *(const s16x8*)ph; fa1h = *(const s16x8*)(ph + 16 * 256);
          fa0l = *(const s16x8*)pl; fa1l = *(const s16x8*)(pl + 16 * 256);
        } else {
          const unsigned short* ph = ibh + (size_t)((lA - 1) * 32 + nrow) * 512 + kb * 32 + quad8;
          const unsigned short* pl = ibl + (size_t)((lA - 1) * 32 + nrow) * 512 + kb * 32 + quad8;
          fa0h = cload(ph); fa1h = cload(ph + 16 * 512);
          fa0l = cload(pl); fa1l = cload(pl + 16 * 512);
        }
      } else {
        const int ko = kb * 32 + quad8 - kinpadA;
        const unsigned short* ph = rbh + (size_t)(lA * 32 + nrow) * 512 + ko;
        const unsigned short* pl = rbl + (size_t)(lA * 32 + nrow) * 512 + ko;
        fa0h = cload(ph); fa1h = cload(ph + 16 * 512);
        fa0l = cload(pl); fa1l = cload(pl + 16 * 512);
      }
      #pragma unroll
      for (int g = 0; g < 4; ++g) {
        const size_t off = ((size_t)(g * 64 + gtb) * nkbA + kb) * 512 + lane * 8;
        s16x8 fbh = *(const s16x8*)(wbh + off);
        s16x8 fbl = *(const s16x8*)(wbl + off);
        acc[g][0] = MFMA16(fa0h, fbh, acc[g][0]);
        acc[g][0] = MFMA16(fa0l, fbh, acc[g][0]);
        acc[g][0] = MFMA16(fa0h, fbl, acc[g][0]);
        acc[g][1] = MFMA16(fa1h, fbh, acc[g][1]);
        acc[g][1] = MFMA16(fa1l, fbh, acc[g][1]);
        acc[g][1] = MFMA16(fa1h, fbl, acc[g][1]);
      }
    }
    #pragma unroll
    for (int g = 0; g < 4; ++g) {
      #pragma unroll
      for (int r = 0; r < 4; ++r) {
        const int m0 = (lane >> 4) * 4 + r;
        exch[kgW][g][utW][m0 * 16 + (lane & 15)]        = acc[g][0][r];
        exch[kgW][g][utW][(m0 + 16) * 16 + (lane & 15)] = acc[g][1][r];
      }
    }
    __syncthreads();

    // ---- fused pointwise: 512 threads x 2 adjacent-u elems; c stays in LDS ----
    {
      const float* bias = Bsrc[lA];
      const float* piv  = PIs[lA];
      const float* pfv  = PFs[lA];
      const float* pov  = POs[lA];
      const int eid0 = tid * 2;
      const int b  = eid0 >> 5;
      const int u0 = eid0 & 31;
      unsigned short mh2[2], ml2[2];
      #pragma unroll
      for (int j = 0; j < 2; ++j) {
        const int u = u0 + j;
        const int ut = u >> 4;
        const int e = b * 16 + (u & 15);
        const int uc = lb * 32 + u;
        float sc = 0.f, si = 0.f, sf = 0.f, so = 0.f;
        #pragma unroll
        for (int kg = 0; kg < 4; ++kg) {
          sc += exch[kg][0][ut][e]; si += exch[kg][1][ut][e];
          sf += exch[kg][2][ut][e]; so += exch[kg][3][ut][e];
        }
        const float cin = sc + bias[uc];
        const float gi  = si + bias[1024 + uc];
        const float gf  = sf + bias[2048 + uc];
        const float go  = so + bias[3072 + uc];
        const float cx  = c_lds[eid0 + j];
        const float ig  = fsig(gi + piv[uc] * cx);
        const float fg  = fsig(gf + pfv[uc] * cx);
        float cy = fg * cx + ig * ftanh(cin);
        cy = fminf(50.0f, fmaxf(-50.0f, cy));
        const float og = fsig(go + pov[uc] * cy);
        const float mv = og * ftanh(cy);
        c_lds[eid0 + j] = cy;
        mh2[j] = f2bf(mv);
        ml2[j] = f2bf(mv - bf2f(mh2[j]));
      }
      const size_t mi = (size_t)(lA * 32 + b) * 1024 + lb * 32 + u0;
      cstore2(mhi + mi, mh2[0], mh2[1]);
      cstore2(mlo + mi, ml2[0], ml2[1]);
    }
    __syncthreads();   // drains vm stores before the flag
    if (tid == 0) {
      __hip_atomic_store(&mflagL[lb * 16], (unsigned int)(t + 1),
                         __ATOMIC_RELAXED, __HIP_MEMORY_SCOPE_AGENT);
    }

    // ============ C-wait: all m(l,t) ready; WAR guard on h(t-4) ============
    if (wv == 0) {
      if (lane < 32) {
        flag_wait_ge(mflagL + lane * 16, (unsigned)(t + 1));
      } else {
        if (lA < 2 && t >= 4) flag_wait_ge(mflagL1 + (lane - 32) * 16, (unsigned)(t - 3));
      }
    }
    __syncthreads();

    // ============ PHASE C: projection ============
    const unsigned short* pph = wPh + (size_t)lA * 524288 + ((size_t)lb * 32) * 512 + lane * 8;
    const unsigned short* ppl = wPl + (size_t)lA * 524288 + ((size_t)lb * 32) * 512 + lane * 8;
    const unsigned short* mah = mhi + (size_t)(lA * 32 + mtW * 16 + nrow) * 1024;
    const unsigned short* mal = mlo + (size_t)(lA * 32 + mtW * 16 + nrow) * 1024;
    f32x4 pacc = {0.f, 0.f, 0.f, 0.f};
    #pragma unroll 2
    for (int kb = kg2W * 8; kb < kg2W * 8 + 8; ++kb) {
      s16x8 fbh = *(const s16x8*)(pph + (size_t)kb * 512);
      s16x8 fbl = *(const s16x8*)(ppl + (size_t)kb * 512);
      const int ko = kb * 32 + quad8;
      s16x8 fah = cload(mah + ko);
      s16x8 fal = cload(mal + ko);
      pacc = MFMA16(fah, fbh, pacc);
      pacc = MFMA16(fal, fbh, pacc);
      pacc = MFMA16(fah, fbl, pacc);
    }
    #pragma unroll
    for (int r = 0; r < 4; ++r) {
      exch[kg2W][0][mtW][((lane >> 4) * 4 + r) * 16 + (lane & 15)] = pacc[r];
    }
    __syncthreads();
    if (tid < 256) {
      const int e0  = tid * 2;
      const int mt  = e0 >> 8;
      const int idx = e0 & 255;
      float v0 = 0.f, v1 = 0.f;
      #pragma unroll
      for (int kg = 0; kg < 4; ++kg) {
        v0 += exch[kg][0][mt][idx];
        v1 += exch[kg][0][mt][idx + 1];
      }
      const int b  = mt * 16 + (idx >> 4);
      const int p0 = idx & 15;
      const size_t hidx = (size_t)(t & 3) * 49152 + (size_t)(lA * 32 + b) * 512 + lb * 16 + p0;
      const unsigned short h0 = f2bf(v0), h1 = f2bf(v1);
      cstore2(hhi + hidx, h0, h1);
      cstore2(hlo + hidx, f2bf(v0 - bf2f(h0)), f2bf(v1 - bf2f(h1)));
      if (lA == 2) {
        float* op = out + ((size_t)t * 32 + b) * 512 + lb * 16 + p0;
        op[0] = v0; op[1] = v1;
      }
    }
    __syncthreads();   // drains h stores before the flag
    if (tid == 0) {
      __hip_atomic_store(&hflagL[lb * 16], (unsigned int)(t + 1),
                         __ATOMIC_RELAXED, __HIP_MEMORY_SCOPE_AGENT);
    }
  }
}

extern "C" void kernel_launch(void* const* d_in, const int* in_sizes, int n_in,
                              void* d_out, int out_size, void* d_ws, size_t ws_size,
                              hipStream_t stream) {
  const float* x   = (const float*)d_in[0];
  const float* W0  = (const float*)d_in[1];
  const float* b0  = (const float*)d_in[2];
  const float* P0  = (const float*)d_in[3];
  const float* pi0 = (const float*)d_in[4];
  const float* pf0 = (const float*)d_in[5];
  const float* po0 = (const float*)d_in[6];
  const float* W1  = (const float*)d_in[7];
  const float* b1  = (const float*)d_in[8];
  const float* P1  = (const float*)d_in[9];
  const float* pi1 = (const float*)d_in[10];
  const float* pf1 = (const float*)d_in[11];
  const float* po1 = (const float*)d_in[12];
  const float* W2  = (const float*)d_in[13];
  const float* b2  = (const float*)d_in[14];
  const float* P2  = (const float*)d_in[15];
  const float* pi2 = (const float*)d_in[16];
  const float* pf2 = (const float*)d_in[17];
  const float* po2 = (const float*)d_in[18];

  hipLaunchKernelGGL(lstmp_persist, dim3(96), dim3(512), 0, stream,
                     x, W0, b0, P0, pi0, pf0, po0,
                     W1, b1, P1, pi1, pf1, po1,
                     W2, b2, P2, pi2, pf2, po2,
                     (float*)d_out, (unsigned char*)d_ws);
}

// Round 7
// 11937.643 us; speedup vs baseline: 1.4681x; 1.4681x over previous
//
#include <hip/hip_runtime.h>

// Persistent wavefront-pipelined LSTMP (3 layers), split-bf16 MFMA emulating fp32.
// Round 7: R4 skeleton (192 blocks x 512thr, 64 thin blocks/layer) + flag-array
// dataflow (no per-step barrier) + deep load pipeline: weight B-frags prefetched
// BEFORE the flag poll (rolling depth-2), h/m cloads batch-issued into register
// arrays. 4-deep h buffers; WAR guard mflag[l+1] >= t-3.

typedef short s16x4 __attribute__((ext_vector_type(4)));
typedef short s16x8 __attribute__((ext_vector_type(8)));
typedef float f32x4 __attribute__((ext_vector_type(4)));

#define MFMA16(a,b,c) __builtin_amdgcn_mfma_f32_16x16x32_bf16((a),(b),(c),0,0,0)

__device__ __forceinline__ unsigned short f2bf(float f) {
  unsigned int u = __builtin_bit_cast(unsigned int, f);
  u += 0x7FFFu + ((u >> 16) & 1u);          // RNE
  return (unsigned short)(u >> 16);
}
__device__ __forceinline__ float bf2f(unsigned short h) {
  unsigned int u = ((unsigned int)h) << 16;
  return __builtin_bit_cast(float, u);
}
__device__ __forceinline__ float fsig(float x)  { return __fdividef(1.0f, 1.0f + __expf(-x)); }
__device__ __forceinline__ float ftanh(float x) { return 1.0f - __fdividef(2.0f, 1.0f + __expf(2.0f * x)); }

// Coherent (LIC) 16B read as two relaxed agent-scope 8B atomic loads.
__device__ __forceinline__ s16x8 cload(const unsigned short* p) {
  unsigned long long a = __hip_atomic_load((unsigned long long*)p,       __ATOMIC_RELAXED, __HIP_MEMORY_SCOPE_AGENT);
  unsigned long long b = __hip_atomic_load((unsigned long long*)(p + 4), __ATOMIC_RELAXED, __HIP_MEMORY_SCOPE_AGENT);
  s16x4 x = __builtin_bit_cast(s16x4, a);
  s16x4 y = __builtin_bit_cast(s16x4, b);
  s16x8 r = {x[0], x[1], x[2], x[3], y[0], y[1], y[2], y[3]};
  return r;
}
__device__ __forceinline__ void cstore1(unsigned short* p, unsigned short v) {
  __hip_atomic_store(p, v, __ATOMIC_RELAXED, __HIP_MEMORY_SCOPE_AGENT);
}
__device__ __forceinline__ void cstore2(unsigned short* p, unsigned short a, unsigned short b) {
  unsigned int v = (unsigned int)a | ((unsigned int)b << 16);
  __hip_atomic_store((unsigned int*)p, v, __ATOMIC_RELAXED, __HIP_MEMORY_SCOPE_AGENT);
}
__device__ __forceinline__ void flag_wait_ge(const unsigned int* f, unsigned int target) {
  while (__hip_atomic_load(f, __ATOMIC_RELAXED, __HIP_MEMORY_SCOPE_AGENT) < target) {
    __builtin_amdgcn_s_sleep(1);
  }
}

// Relaxed sense-counting grid barrier (init only; 192 blocks).
__device__ __forceinline__ void gbar(unsigned int* bar, unsigned int* rel, unsigned int seq) {
  __syncthreads();
  asm volatile("" ::: "memory");
  if (blockIdx.x == 0) {
    const int tid = threadIdx.x;
    if (tid > 0 && tid < 192) {
      while (__hip_atomic_load(&bar[tid * 16], __ATOMIC_RELAXED, __HIP_MEMORY_SCOPE_AGENT) != seq) {
        __builtin_amdgcn_s_sleep(1);
      }
    }
    __syncthreads();
    if (tid == 0) {
      __hip_atomic_store(rel, seq, __ATOMIC_RELAXED, __HIP_MEMORY_SCOPE_AGENT);
    }
  } else {
    if (threadIdx.x == 0) {
      __hip_atomic_store(&bar[blockIdx.x * 16], seq, __ATOMIC_RELAXED, __HIP_MEMORY_SCOPE_AGENT);
      while (__hip_atomic_load(rel, __ATOMIC_RELAXED, __HIP_MEMORY_SCOPE_AGENT) != seq) {
        __builtin_amdgcn_s_sleep(1);
      }
    }
    __syncthreads();
  }
  asm volatile("" ::: "memory");
}

__global__ __launch_bounds__(512) void lstmp_persist(
    const float* __restrict__ x,
    const float* __restrict__ W0, const float* __restrict__ b0, const float* __restrict__ P0,
    const float* __restrict__ pi0, const float* __restrict__ pf0, const float* __restrict__ po0,
    const float* __restrict__ W1, const float* __restrict__ b1, const float* __restrict__ P1,
    const float* __restrict__ pi1, const float* __restrict__ pf1, const float* __restrict__ po1,
    const float* __restrict__ W2, const float* __restrict__ b2, const float* __restrict__ P2,
    const float* __restrict__ pi2, const float* __restrict__ pf2, const float* __restrict__ po2,
    float* __restrict__ out, unsigned char* __restrict__ ws)
{
  const int tid  = threadIdx.x;
  const int bid  = blockIdx.x;
  const int lane = tid & 63;
  const int wv   = tid >> 6;             // 0..7
  const int quad8 = (lane >> 4) * 8;
  const int nrow  = lane & 15;

  // ---- workspace carve ----
  unsigned int* bar    = (unsigned int*)ws;   // 192*16 = 3072
  unsigned int* rel    = bar + 3072;
  unsigned int* mflag0 = bar + 3104;          // 3*64 flags, 16-uint spaced = 3072
  unsigned int* hflag0 = mflag0 + 3072;       // 3*64 flags, 16-uint spaced = 3072
  unsigned short* xhi = (unsigned short*)(ws + 40960);
  unsigned short* xlo  = xhi  + 4096000;   // 500*32*256
  unsigned short* hhi  = xlo  + 4096000;   // 4 bufs * 3*32*512 = 196608
  unsigned short* hlo  = hhi  + 196608;
  unsigned short* mhi  = hlo  + 196608;    // 3*32*1024
  unsigned short* mlo  = mhi  + 98304;
  unsigned short* wBh0 = mlo  + 98304;     // 256*24*512
  unsigned short* wBl0 = wBh0 + 3145728;
  unsigned short* wBh1 = wBl0 + 3145728;   // 256*32*512
  unsigned short* wBl1 = wBh1 + 4194304;
  unsigned short* wBh2 = wBl1 + 4194304;
  unsigned short* wBl2 = wBh2 + 4194304;
  unsigned short* wPh  = wBl2 + 4194304;   // 3 * 32*32*512
  unsigned short* wPl  = wPh  + 1572864;

  const float* Wsrc[3] = {W0, W1, W2};
  const float* Psrc[3] = {P0, P1, P2};
  const float* Bsrc[3] = {b0, b1, b2};
  const float* PIs[3]  = {pi0, pi1, pi2};
  const float* PFs[3]  = {pf0, pf1, pf2};
  const float* POs[3]  = {po0, po1, po2};
  unsigned short* wBhv[3] = {wBh0, wBh1, wBh2};
  unsigned short* wBlv[3] = {wBl0, wBl1, wBl2};
  const int NKBv[3]    = {24, 32, 32};
  const int NKBINv[3]  = {8, 16, 16};
  const int KINPADv[3] = {256, 512, 512};
  const int KWv[3]     = {752, 1024, 1024};
  const int NINv[3]    = {240, 512, 512};

  __shared__ float exch[8][4][512];  // 64 KB per-wave partial sums
  __shared__ float c_lds[512];       // persistent cell state
  __shared__ float lds_pad[4096];    // 16 KB pad -> ~82 KB total -> 1 block/CU
  ((volatile float*)lds_pad)[tid & 4095] = 0.0f;

  const unsigned int NT = 192u * 512u;
  const unsigned int gtid = (unsigned int)bid * 512u + (unsigned int)tid;

  // ================= INIT (ws re-poisoned every launch) =================
  for (unsigned int i = gtid; i < 6144u; i += NT) mflag0[i] = 0;  // m+h flags
  for (unsigned int i = gtid; i < 4096000u; i += NT) {
    unsigned int k = i & 255u, tb = i >> 8;
    float v = (k < 240u) ? x[tb * 240u + k] : 0.0f;
    unsigned short h = f2bf(v);
    xhi[i] = h; xlo[i] = f2bf(v - bf2f(h));
  }
  for (unsigned int i = gtid; i < 196608u; i += NT) { hhi[i] = 0; hlo[i] = 0; }
  for (int l = 0; l < 3; ++l) {
    const unsigned int nkb = (unsigned int)NKBv[l];
    const unsigned int tot = 256u * nkb * 512u;
    const float* Wl = Wsrc[l];
    unsigned short* dh = wBhv[l];
    unsigned short* dl = wBlv[l];
    const int kinpad = KINPADv[l], kw = KWv[l], nin = NINv[l];
    for (unsigned int i = gtid; i < tot; i += NT) {
      unsigned int j  = i & 7u;
      unsigned int ln = (i >> 3) & 63u;
      unsigned int kb = (i >> 9) % nkb;
      unsigned int gt = i / (nkb * 512u);
      unsigned int g  = gt * 16u + (ln & 15u);
      int k = (int)(kb * 32u + ((ln >> 4) * 8u) + j);
      float v;
      if (k < kinpad) v = (l == 0 && k >= 240) ? 0.0f : Wl[(size_t)g * kw + k];
      else            v = Wl[(size_t)g * kw + (k - kinpad + nin)];
      unsigned short h = f2bf(v);
      dh[i] = h; dl[i] = f2bf(v - bf2f(h));
    }
  }
  for (int l = 0; l < 3; ++l) {
    const float* Pl = Psrc[l];
    unsigned short* dh = wPh + (size_t)l * 524288u;
    unsigned short* dl = wPl + (size_t)l * 524288u;
    for (unsigned int i = gtid; i < 524288u; i += NT) {
      unsigned int j  = i & 7u;
      unsigned int ln = (i >> 3) & 63u;
      unsigned int kb = (i >> 9) & 31u;
      unsigned int pt = i >> 14;
      unsigned int prow = pt * 16u + (ln & 15u);
      int k = (int)(kb * 32u + ((ln >> 4) * 8u) + j);
      float v = Pl[(size_t)prow * 1024u + k];
      unsigned short h = f2bf(v);
      dh[i] = h; dl[i] = f2bf(v - bf2f(h));
    }
  }
  if (tid < 512) c_lds[tid] = 0.0f;

  __builtin_amdgcn_fence(__ATOMIC_RELEASE, "agent");
  gbar(bar, rel, 1u);
  __builtin_amdgcn_fence(__ATOMIC_ACQUIRE, "agent");

  // ---- fixed per-block roles (grid = 192 = 3 layers x 64 blocks) ----
  const int lA  = bid >> 6;          // layer 0..2
  const int utA = bid & 63;          // 16-unit tile (phase A)
  const int ptC = (bid & 63) >> 1;   // proj 16-col tile (phase C)
  const int mtC = bid & 1;           // batch half (phase C)

  const int nkbA    = NKBv[lA];
  const int nkbinA  = NKBINv[lA];
  const int kinpadA = KINPADv[lA];
  const int kbwA    = nkbA >> 3;     // k-blocks per wave: 3 or 4

  unsigned int* mflagL  = mflag0 + lA * 1024;
  unsigned int* mflagL1 = mflag0 + (lA + 1) * 1024;   // valid when lA<2
  unsigned int* hflagL  = hflag0 + lA * 1024;
  unsigned int* hflagLm = hflag0 + (lA - 1) * 1024;   // valid when lA>0

  const unsigned short* wbh = wBhv[lA];
  const unsigned short* wbl = wBlv[lA];

  for (int t = 0; t < 500; ++t) {
    const unsigned short* ibh = hhi + (size_t)(t & 3) * 49152;        // h_{l-1}(t)
    const unsigned short* ibl = hlo + (size_t)(t & 3) * 49152;
    const unsigned short* rbh = hhi + (size_t)((t + 3) & 3) * 49152;  // h_l(t-1)
    const unsigned short* rbl = hlo + (size_t)((t + 3) & 3) * 49152;
    const int kb0 = wv * kbwA;

    // ---- B-frag prefetch (weights: flag-independent), rolling depth-2 ----
    s16x8 Bh[2][4], Bl[2][4];
    auto loadB = [&](int slot, int kb) {
      #pragma unroll
      for (int g = 0; g < 4; ++g) {
        const size_t off = ((size_t)(g * 64 + utA) * nkbA + kb) * 512 + lane * 8;
        Bh[slot][g] = *(const s16x8*)(wbh + off);
        Bl[slot][g] = *(const s16x8*)(wbl + off);
      }
    };
    loadB(0, kb0);
    loadB(1, kb0 + 1);

    // ---- A-wait: h_{l-1}(t) ready (wv0) AND own h(t-1) ready (wv1) ----
    if (wv == 0) {
      if (lA > 0) flag_wait_ge(hflagLm + lane * 16, (unsigned)(t + 1));
    } else if (wv == 1) {
      if (t > 0)  flag_wait_ge(hflagL + lane * 16, (unsigned)t);
    }
    __syncthreads();

    // ---- batch-issue ALL A-side loads into register arrays ----
    s16x8 Ah[4][2], Al[4][2];
    #pragma unroll
    for (int j = 0; j < 4; ++j) {
      if (j < kbwA) {
        const int kb = kb0 + j;
        if (kb < nkbinA) {
          if (lA == 0) {
            const unsigned short* ph = xhi + (size_t)(t * 32 + nrow) * 256 + kb * 32 + quad8;
            const unsigned short* pl = xlo + (size_t)(t * 32 + nrow) * 256 + kb * 32 + quad8;
            Ah[j][0] = *(const s16x8*)ph; Ah[j][1] = *(const s16x8*)(ph + 16 * 256);
            Al[j][0] = *(const s16x8*)pl; Al[j][1] = *(const s16x8*)(pl + 16 * 256);
          } else {
            const unsigned short* ph = ibh + (size_t)((lA - 1) * 32 + nrow) * 512 + kb * 32 + quad8;
            const unsigned short* pl = ibl + (size_t)((lA - 1) * 32 + nrow) * 512 + kb * 32 + quad8;
            Ah[j][0] = cload(ph); Ah[j][1] = cload(ph + 16 * 512);
            Al[j][0] = cload(pl); Al[j][1] = cload(pl + 16 * 512);
          }
        } else {
          const int ko = kb * 32 + quad8 - kinpadA;
          const unsigned short* ph = rbh + (size_t)(lA * 32 + nrow) * 512 + ko;
          const unsigned short* pl = rbl + (size_t)(lA * 32 + nrow) * 512 + ko;
          Ah[j][0] = cload(ph); Ah[j][1] = cload(ph + 16 * 512);
          Al[j][0] = cload(pl); Al[j][1] = cload(pl + 16 * 512);
        }
      }
    }

    // ---- gates MFMA with rolling B reload ----
    f32x4 acc[4][2];
    #pragma unroll
    for (int g = 0; g < 4; ++g) { acc[g][0] = {0.f,0.f,0.f,0.f}; acc[g][1] = {0.f,0.f,0.f,0.f}; }
    #pragma unroll
    for (int j = 0; j < 4; ++j) {
      if (j < kbwA) {
        const int slot = j & 1;
        #pragma unroll
        for (int g = 0; g < 4; ++g) {
          acc[g][0] = MFMA16(Ah[j][0], Bh[slot][g], acc[g][0]);
          acc[g][0] = MFMA16(Al[j][0], Bh[slot][g], acc[g][0]);
          acc[g][0] = MFMA16(Ah[j][0], Bl[slot][g], acc[g][0]);
          acc[g][1] = MFMA16(Ah[j][1], Bh[slot][g], acc[g][1]);
          acc[g][1] = MFMA16(Al[j][1], Bh[slot][g], acc[g][1]);
          acc[g][1] = MFMA16(Ah[j][1], Bl[slot][g], acc[g][1]);
        }
        if (j + 2 < kbwA) loadB(slot, kb0 + j + 2);
      }
    }
    #pragma unroll
    for (int g = 0; g < 4; ++g) {
      #pragma unroll
      for (int r = 0; r < 4; ++r) {
        const int m0 = (lane >> 4) * 4 + r;
        exch[wv][g][m0 * 16 + (lane & 15)]        = acc[g][0][r];
        exch[wv][g][(m0 + 16) * 16 + (lane & 15)] = acc[g][1][r];
      }
    }
    __syncthreads();

    // ---- fused pointwise: 512 threads, 1 (b,u) each ----
    {
      const float* bias = Bsrc[lA];
      const float* piv  = PIs[lA];
      const float* pfv  = PFs[lA];
      const float* pov  = POs[lA];
      const int e = tid, b = tid >> 4, u = tid & 15;
      const int uc = utA * 16 + u;
      float sc = 0.f, si = 0.f, sf = 0.f, so = 0.f;
      #pragma unroll
      for (int w = 0; w < 8; ++w) {
        sc += exch[w][0][e]; si += exch[w][1][e];
        sf += exch[w][2][e]; so += exch[w][3][e];
      }
      const float cin = sc + bias[uc];
      const float gi  = si + bias[1024 + uc];
      const float gf  = sf + bias[2048 + uc];
      const float go  = so + bias[3072 + uc];
      const float cx  = c_lds[e];
      const float ig  = fsig(gi + piv[uc] * cx);
      const float fg  = fsig(gf + pfv[uc] * cx);
      float cy = fg * cx + ig * ftanh(cin);
      cy = fminf(50.0f, fmaxf(-50.0f, cy));
      const float og = fsig(go + pov[uc] * cy);
      const float mv = og * ftanh(cy);
      c_lds[e] = cy;
      const unsigned short mh = f2bf(mv);
      const size_t mi = (size_t)(lA * 32 + b) * 1024 + uc;
      cstore1(mhi + mi, mh);
      cstore1(mlo + mi, f2bf(mv - bf2f(mh)));
    }
    __syncthreads();   // drains vm stores before the flag
    if (tid == 0) {
      __hip_atomic_store(&mflagL[utA * 16], (unsigned int)(t + 1),
                         __ATOMIC_RELAXED, __HIP_MEMORY_SCOPE_AGENT);
    }

    // ============ PHASE C: projection (8 waves split K=32kb) ============
    // preload proj weight frags (independent of m) before the poll
    const unsigned short* pph = wPh + (size_t)lA * 524288 + ((size_t)ptC * 32) * 512 + lane * 8;
    const unsigned short* ppl = wPl + (size_t)lA * 524288 + ((size_t)ptC * 32) * 512 + lane * 8;
    s16x8 pbh[4], pbl[4];
    #pragma unroll
    for (int j = 0; j < 4; ++j) {
      const int kb = wv * 4 + j;
      pbh[j] = *(const s16x8*)(pph + (size_t)kb * 512);
      pbl[j] = *(const s16x8*)(ppl + (size_t)kb * 512);
    }
    // C-wait: all 64 m-producers (wv0); WAR guard on h(t-4) (wv1)
    if (wv == 0) {
      flag_wait_ge(mflagL + lane * 16, (unsigned)(t + 1));
    } else if (wv == 1) {
      if (lA < 2 && t >= 4) flag_wait_ge(mflagL1 + lane * 16, (unsigned)(t - 3));
    }
    __syncthreads();

    // batch-issue all m cloads
    const unsigned short* mah = mhi + (size_t)(lA * 32 + mtC * 16 + nrow) * 1024;
    const unsigned short* mal = mlo + (size_t)(lA * 32 + mtC * 16 + nrow) * 1024;
    s16x8 fmh[4], fml[4];
    #pragma unroll
    for (int j = 0; j < 4; ++j) {
      const int ko = (wv * 4 + j) * 32 + quad8;
      fmh[j] = cload(mah + ko);
      fml[j] = cload(mal + ko);
    }
    f32x4 pacc = {0.f, 0.f, 0.f, 0.f};
    #pragma unroll
    for (int j = 0; j < 4; ++j) {
      pacc = MFMA16(fmh[j], pbh[j], pacc);
      pacc = MFMA16(fml[j], pbh[j], pacc);
      pacc = MFMA16(fmh[j], pbl[j], pacc);
    }
    #pragma unroll
    for (int r = 0; r < 4; ++r) {
      exch[wv][0][((lane >> 4) * 4 + r) * 16 + (lane & 15)] = pacc[r];
    }
    __syncthreads();
    if (tid < 128) {
      const int r  = tid >> 3;           // 0..15 batch row within half
      const int pg = (tid & 7) * 2;      // even proj col
      const int e0 = r * 16 + pg;
      float v0 = 0.f, v1 = 0.f;
      #pragma unroll
      for (int w = 0; w < 8; ++w) { v0 += exch[w][0][e0]; v1 += exch[w][0][e0 + 1]; }
      const int b = mtC * 16 + r;
      const int p = ptC * 16 + pg;
      const size_t hidx = (size_t)(t & 3) * 49152 + (size_t)(lA * 32 + b) * 512 + p;
      const unsigned short h0 = f2bf(v0), h1 = f2bf(v1);
      cstore2(hhi + hidx, h0, h1);
      cstore2(hlo + hidx, f2bf(v0 - bf2f(h0)), f2bf(v1 - bf2f(h1)));
      if (lA == 2) {
        float* op = out + ((size_t)t * 32 + b) * 512 + p;
        op[0] = v0; op[1] = v1;
      }
    }
    __syncthreads();   // drains h stores before the flag
    if (tid == 0) {
      __hip_atomic_store(&hflagL[(bid & 63) * 16], (unsigned int)(t + 1),
                         __ATOMIC_RELAXED, __HIP_MEMORY_SCOPE_AGENT);
    }
  }
}

extern "C" void kernel_launch(void* const* d_in, const int* in_sizes, int n_in,
                              void* d_out, int out_size, void* d_ws, size_t ws_size,
                              hipStream_t stream) {
  const float* x   = (const float*)d_in[0];
  const float* W0  = (const float*)d_in[1];
  const float* b0  = (const float*)d_in[2];
  const float* P0  = (const float*)d_in[3];
  const float* pi0 = (const float*)d_in[4];
  const float* pf0 = (const float*)d_in[5];
  const float* po0 = (const float*)d_in[6];
  const float* W1  = (const float*)d_in[7];
  const float* b1  = (const float*)d_in[8];
  const float* P1  = (const float*)d_in[9];
  const float* pi1 = (const float*)d_in[10];
  const float* pf1 = (const float*)d_in[11];
  const float* po1 = (const float*)d_in[12];
  const float* W2  = (const float*)d_in[13];
  const float* b2  = (const float*)d_in[14];
  const float* P2  = (const float*)d_in[15];
  const float* pi2 = (const float*)d_in[16];
  const float* pf2 = (const float*)d_in[17];
  const float* po2 = (const float*)d_in[18];

  hipLaunchKernelGGL(lstmp_persist, dim3(192), dim3(512), 0, stream,
                     x, W0, b0, P0, pi0, pf0, po0,
                     W1, b1, P1, pi1, pf1, po1,
                     W2, b2, P2, pi2, pf2, po2,
                     (float*)d_out, (unsigned char*)d_ws);
}